// Round 5
// baseline (375.364 us; speedup 1.0000x reference)
//
#include <hip/hip_runtime.h>

// out[1,8192] = x[1,8192] @ W[8192,8192] + b[8192]   (all fp32)
// R5 theory: previous kernels read W in 4KB chunks strided 32KB with all
// blocks phase-aligned mod the HBM channel interleave -> ~8-30 of ~128
// channels active at any instant -> 2.3 TB/s (1/3 of fill's 6.7 TB/s).
// Fix: flat grid-stride stream (the fill's own pattern). Thread g reads
// float4 at {g, g+G, g+2G, ...}; the GPU's instantaneous window is a
// contiguous 4MB stripe sweeping W -> all channels covered at any phase.
// Since G = 128 rows x 2048 float4, each thread keeps one fixed column
// and accumulates rows {g/2048 + 128k}: split-K with 128 row-groups.

#define IN_LEN   8192
#define OUT_LEN  8192
#define THREADS  256
#define BLOCKS   1024
#define G        (BLOCKS * THREADS)      // 262144 threads = 128 rows x 2048 col4
#define NCOL4    (OUT_LEN / 4)           // 2048
#define RGROUPS  (G / NCOL4)             // 128 row-groups (splits)
#define ITERS    (IN_LEN / RGROUPS)      // 64 rows per thread

__global__ __launch_bounds__(THREADS, 4)
void matvec_stage1(const float* __restrict__ x,
                   const float* __restrict__ W,
                   float* __restrict__ ws) {
    const int g       = blockIdx.x * THREADS + threadIdx.x;
    const int col4    = g & (NCOL4 - 1);     // fixed column per thread
    const int rowbase = g >> 11;             // g / 2048, uniform per block

    // This block needs x[rowbase + k*RGROUPS], k = 0..ITERS-1
    __shared__ float xs[ITERS];
    if (threadIdx.x < ITERS) xs[threadIdx.x] = x[rowbase + threadIdx.x * RGROUPS];
    __syncthreads();

    const float4* __restrict__ W4 = (const float4*)W;
    float4 acc = make_float4(0.f, 0.f, 0.f, 0.f);

    size_t p = (size_t)g;                    // flat float4 index; stride G
#pragma unroll 8
    for (int s = 0; s < ITERS; ++s) {
        const float4 w  = W4[p];
        const float  xv = xs[s];
        p += G;
        acc.x += xv * w.x;
        acc.y += xv * w.y;
        acc.z += xv * w.z;
        acc.w += xv * w.w;
    }

    // partials: ws[rowgroup][OUT_LEN]; 8 blocks share a rowgroup, each
    // owns a distinct 256-col4 slice -> unique coalesced float4 stores.
    ((float4*)ws)[(size_t)rowbase * NCOL4 + col4] = acc;
}

// out[col] = sum over 128 row-group partials + bias. 4 MB read.
__global__ __launch_bounds__(THREADS)
void matvec_stage2(const float* __restrict__ ws,
                   const float* __restrict__ b,
                   float* __restrict__ out) {
    const int col = blockIdx.x * THREADS + threadIdx.x;
    float s = 0.f;
#pragma unroll 8
    for (int r = 0; r < RGROUPS; ++r)        // lanes read consecutive cols: coalesced
        s += ws[(size_t)r * OUT_LEN + col];
    out[col] = s + b[col];
}

extern "C" void kernel_launch(void* const* d_in, const int* in_sizes, int n_in,
                              void* d_out, int out_size, void* d_ws, size_t ws_size,
                              hipStream_t stream) {
    const float* x = (const float*)d_in[0];   // (1, 8192)
    const float* W = (const float*)d_in[1];   // (8192, 8192) row-major
    const float* b = (const float*)d_in[2];   // (8192,)
    float* out = (float*)d_out;               // (1, 8192)
    float* ws  = (float*)d_ws;                // >= RGROUPS*OUT_LEN*4 = 4 MB

    matvec_stage1<<<dim3(BLOCKS), dim3(THREADS), 0, stream>>>(x, W, ws);
    matvec_stage2<<<dim3(OUT_LEN / THREADS), dim3(THREADS), 0, stream>>>(ws, b, out);
}